// Round 5
// baseline (961.834 us; speedup 1.0000x reference)
//
#include <hip/hip_runtime.h>
#include <hip/hip_bf16.h>

// PConvLinear: B=2, N=60000, K=16, C_in=64, C_add=3, C_mid=16.
// pconv[p][c][m] = sum_k feat[p][k][c] * Wn[p][k][m]   (c in 0..66)
// out[p][o]     = sum_f pconv_flat[p][f] * LW[o][f] + bias[o],  f = c*16+m, F=1072
#define NPTS   60000
#define TOTP   120000
#define FP     1088          // F padded to 34*32
#define KSTR   20            // sT row stride (f16): 8B-aligned b64 reads
#define PSTR   1096          // fused-fallback sP stride

typedef _Float16 f16x8 __attribute__((ext_vector_type(8)));
typedef _Float16 f16x4 __attribute__((ext_vector_type(4)));
typedef float    f32x4 __attribute__((ext_vector_type(4)));

// ---- linear_weight fp32 [128][1072] -> f16 [128][1088] in d_ws ----
__global__ void __launch_bounds__(256)
cvt_lw_kernel(const float* __restrict__ LW, _Float16* __restrict__ LWh) {
    const int o = blockIdx.x;
    for (int f = threadIdx.x; f < FP; f += 256)
        LWh[o * FP + f] = (f < 1072) ? (_Float16)LW[o * 1072 + f] : (_Float16)0.f;
}

// =====================================================================
// Kernel 1: gather + pconv -> P f16 [chunkN][1088]. No sP, no barrier.
// 256 thr = 4 waves; wave w handles points pblk + w*2 + {0,1}.
// =====================================================================
__global__ void __launch_bounds__(256, 8)
pconv_gather(const float* __restrict__ inF,   // [2][60000][64]
             const int*   __restrict__ inds,  // [120000][16]
             const float* __restrict__ Wn,    // [120000][16][16]
             const float* __restrict__ addF,  // [120000][16][3]
             _Float16*    __restrict__ P,     // [chunkN][1088]
             int p0)                          // chunk start (global point)
{
    __shared__ __align__(16) _Float16 sT[4][32 * KSTR];

    const int t    = threadIdx.x;
    const int lane = t & 63;
    const int w    = t >> 6;
    const int q    = lane >> 4;
    const int ml   = lane & 15;
    const bool qlo = (q < 2);

    const int pblk = p0 + blockIdx.x * 8;          // block's first global point
    const int bOff = (pblk / NPTS) * NPTS;         // batch row base for gather
    const int pw   = pblk + w * 2;                 // wave's first point

    const f32x4 z4 = {0.f, 0.f, 0.f, 0.f};

    // lane l holds inds[point pw + (l>>4 & 1)][k = l&15]  (lanes 32-63 duplicate)
    const int ind_lane = inds[pw * 16 + (lane & 31)];

    const int k0  = (lane >> 3) * 2;   // even row pair gathered by this lane
    const int seg = lane & 7;          // 4-float segment of the 32-c half
    _Float16* T = &sT[w][0];

    for (int i = 0; i < 2; ++i) {
        const int p       = pw + i;
        const int base_nk = p * 16;

        f16x8 bf = {0,0,0,0,0,0,0,0};
        if (qlo) {
            #pragma unroll
            for (int j = 0; j < 8; ++j)
                bf[j] = (_Float16)Wn[(base_nk + q * 8 + j) * 16 + ml];
        }
        f16x8 afr = {0,0,0,0,0,0,0,0};
        if (qlo && ml < 3) {
            #pragma unroll
            for (int j = 0; j < 8; ++j)
                afr[j] = (_Float16)addF[(base_nk + q * 8 + j) * 3 + ml];
        }

        const int idx0 = __shfl(ind_lane, i * 16 + k0,     64);
        const int idx1 = __shfl(ind_lane, i * 16 + k0 + 1, 64);
        _Float16* Prow = P + (long)(p - p0) * FP;

        #pragma unroll
        for (int ch = 0; ch < 2; ++ch) {      // two 32-channel halves of c=0..63
            const float4 v0 = *(const float4*)(inF + (bOff + idx0) * 64 + ch * 32 + seg * 4);
            const float4 v1 = *(const float4*)(inF + (bOff + idx1) * 64 + ch * 32 + seg * 4);
            {
                const float a0[4] = {v0.x, v0.y, v0.z, v0.w};
                const float a1[4] = {v1.x, v1.y, v1.z, v1.w};
                #pragma unroll
                for (int cc = 0; cc < 4; ++cc) {
                    union { _Float16 h[2]; unsigned u; } pk;
                    pk.h[0] = (_Float16)a0[cc];
                    pk.h[1] = (_Float16)a1[cc];
                    *(unsigned*)&T[(seg * 4 + cc) * KSTR + k0] = pk.u;
                }
            }
            #pragma unroll
            for (int h = 0; h < 2; ++h) {     // 2 c-tiles per half
                f16x8 a = {0,0,0,0,0,0,0,0};
                if (qlo) {
                    const _Float16* ap = T + (h * 16 + ml) * KSTR + q * 8;
                    const f16x4 alo = *(const f16x4*)ap;
                    const f16x4 ahi = *(const f16x4*)(ap + 4);
                    a[0]=alo[0]; a[1]=alo[1]; a[2]=alo[2]; a[3]=alo[3];
                    a[4]=ahi[0]; a[5]=ahi[1]; a[6]=ahi[2]; a[7]=ahi[3];
                }
                const f32x4 d = __builtin_amdgcn_mfma_f32_16x16x32_f16(a, bf, z4, 0, 0, 0);
                const int ct = ch * 2 + h;
                #pragma unroll
                for (int r = 0; r < 4; ++r)
                    Prow[(ct * 16 + q * 4 + r) * 16 + ml] = (_Float16)d[r];
            }
        }
        // c-tile 4: c=64..66 real, c=67 zero -> fills f in [1024,1088)
        {
            const f32x4 d = __builtin_amdgcn_mfma_f32_16x16x32_f16(afr, bf, z4, 0, 0, 0);
            if (q == 0) {
                #pragma unroll
                for (int r = 0; r < 4; ++r)
                    Prow[(64 + r) * 16 + ml] = (_Float16)d[r];
            }
        }
    }
}

// =====================================================================
// Kernel 2: out[chunkN x 128] = P @ LWh^T + bias. No LDS, no barriers.
// 256 thr = 4 waves; wave w owns 32 points (pl0 = blk*128 + w*32), all 128 outs.
// =====================================================================
__global__ void __launch_bounds__(256, 4)
linear_mfma(const _Float16* __restrict__ P,    // [chunkN][1088]
            const _Float16* __restrict__ LWh,  // [128][1088]
            const float*    __restrict__ bias, // [128]
            float*          __restrict__ out,  // [120000][128]
            int p0, int chunkN)
{
    const int t    = threadIdx.x;
    const int lane = t & 63;
    const int w    = t >> 6;
    const int q    = lane >> 4;
    const int ml   = lane & 15;

    const int pl0 = blockIdx.x * 128 + w * 32;

    int rA = pl0 + ml;       if (rA >= chunkN) rA = chunkN - 1;
    int rB = pl0 + 16 + ml;  if (rB >= chunkN) rB = chunkN - 1;
    const _Float16* aPA = P + (long)rA * FP + q * 8;
    const _Float16* aPB = P + (long)rB * FP + q * 8;
    const _Float16* bP  = LWh + ml * FP + q * 8;

    const f32x4 z4 = {0.f,0.f,0.f,0.f};
    f32x4 accA[4], accB[4];
    #pragma unroll
    for (int ot = 0; ot < 4; ++ot) { accA[ot] = z4; accB[ot] = z4; }
    f32x4 accA2[4], accB2[4];
    #pragma unroll
    for (int ot = 0; ot < 4; ++ot) { accA2[ot] = z4; accB2[ot] = z4; }

    #pragma unroll 2
    for (int ch = 0; ch < 34; ++ch) {
        const int kb = ch * 32;
        const f16x8 aA = *(const f16x8*)(aPA + kb);   // P rows, L3-hot
        const f16x8 aB = *(const f16x8*)(aPB + kb);
        #pragma unroll
        for (int ot = 0; ot < 4; ++ot) {              // o-tiles 0..3
            const f16x8 b = *(const f16x8*)(bP + (ot * 16) * FP + kb);
            accA[ot] = __builtin_amdgcn_mfma_f32_16x16x32_f16(aA, b, accA[ot], 0, 0, 0);
            accB[ot] = __builtin_amdgcn_mfma_f32_16x16x32_f16(aB, b, accB[ot], 0, 0, 0);
        }
        #pragma unroll
        for (int ot = 0; ot < 4; ++ot) {              // o-tiles 4..7
            const f16x8 b = *(const f16x8*)(bP + ((ot + 4) * 16) * FP + kb);
            accA2[ot] = __builtin_amdgcn_mfma_f32_16x16x32_f16(aA, b, accA2[ot], 0, 0, 0);
            accB2[ot] = __builtin_amdgcn_mfma_f32_16x16x32_f16(aB, b, accB2[ot], 0, 0, 0);
        }
    }

    // epilogue: D rows q*4+r = points pl0(+16) + q*4+r, cols ot*16+ml
    const int pAr = pl0 + q * 4;
    const int pBr = pAr + 16;
    #pragma unroll
    for (int ot = 0; ot < 8; ++ot) {
        const f32x4 vA = (ot < 4) ? accA[ot & 3] : accA2[ot & 3];
        const f32x4 vB = (ot < 4) ? accB[ot & 3] : accB2[ot & 3];
        const float bz = bias[ot * 16 + ml];
        #pragma unroll
        for (int r = 0; r < 4; ++r) {
            if (pAr + r < chunkN)
                out[(long)(p0 + pAr + r) * 128 + ot * 16 + ml] = vA[r] + bz;
            if (pBr + r < chunkN)
                out[(long)(p0 + pBr + r) * 128 + ot * 16 + ml] = vB[r] + bz;
        }
    }
}

// =====================================================================
// Fused fallback (R3 kernel, 356 us) — used only if ws_size is tiny.
// =====================================================================
__global__ void __launch_bounds__(256, 4)
pconv_linear_fused(const float* __restrict__ inF, const int* __restrict__ inds,
                   const float* __restrict__ Wn, const float* __restrict__ addF,
                   const _Float16* __restrict__ LWh, const float* __restrict__ bias,
                   float* __restrict__ out)
{
    __shared__ __align__(16) _Float16 sP[16 * PSTR];
    __shared__ __align__(16) _Float16 sT[4][32 * KSTR];

    const int t = threadIdx.x, lane = t & 63, w = t >> 6;
    const int q = lane >> 4, ml = lane & 15;
    const bool qlo = (q < 2);
    const int bid = blockIdx.x, b = bid / 3750, n0 = (bid - b * 3750) * 16;
    const int bN = b * NPTS;
    const f32x4 z4 = {0.f,0.f,0.f,0.f};

    const int ind_lane = inds[(bN + n0 + w * 4) * 16 + lane];
    _Float16* T = &sT[w][0];
    const int k0 = (lane >> 3) * 2, seg = lane & 7;

    for (int i = 0; i < 4; ++i) {
        const int p = w * 4 + i;
        const int base_nk = (bN + n0 + p) * 16;
        f16x8 bf = {0,0,0,0,0,0,0,0};
        if (qlo) {
            #pragma unroll
            for (int j = 0; j < 8; ++j)
                bf[j] = (_Float16)Wn[(base_nk + q * 8 + j) * 16 + ml];
        }
        f16x8 afA = {0,0,0,0,0,0,0,0};
        if (qlo && ml < 3) {
            #pragma unroll
            for (int j = 0; j < 8; ++j)
                afA[j] = (_Float16)addF[(base_nk + q * 8 + j) * 3 + ml];
        }
        #pragma unroll
        for (int ch = 0; ch < 2; ++ch) {
            const int idx0 = __shfl(ind_lane, i * 16 + k0, 64);
            const int idx1 = __shfl(ind_lane, i * 16 + k0 + 1, 64);
            const float4 v0 = *(const float4*)(inF + (bN + idx0) * 64 + ch * 32 + seg * 4);
            const float4 v1 = *(const float4*)(inF + (bN + idx1) * 64 + ch * 32 + seg * 4);
            {
                const float a0[4] = {v0.x, v0.y, v0.z, v0.w};
                const float a1[4] = {v1.x, v1.y, v1.z, v1.w};
                #pragma unroll
                for (int cc = 0; cc < 4; ++cc) {
                    union { _Float16 h[2]; unsigned u; } pk;
                    pk.h[0] = (_Float16)a0[cc]; pk.h[1] = (_Float16)a1[cc];
                    *(unsigned*)&T[(seg * 4 + cc) * KSTR + k0] = pk.u;
                }
            }
            #pragma unroll
            for (int h = 0; h < 2; ++h) {
                f16x8 a = {0,0,0,0,0,0,0,0};
                if (qlo) {
                    const _Float16* ap = T + (h * 16 + ml) * KSTR + q * 8;
                    const f16x4 alo = *(const f16x4*)ap;
                    const f16x4 ahi = *(const f16x4*)(ap + 4);
                    a[0]=alo[0]; a[1]=alo[1]; a[2]=alo[2]; a[3]=alo[3];
                    a[4]=ahi[0]; a[5]=ahi[1]; a[6]=ahi[2]; a[7]=ahi[3];
                }
                const f32x4 d = __builtin_amdgcn_mfma_f32_16x16x32_f16(a, bf, z4, 0, 0, 0);
                const int ct = ch * 2 + h;
                #pragma unroll
                for (int r = 0; r < 4; ++r)
                    sP[p * PSTR + (ct * 16 + q * 4 + r) * 16 + ml] = (_Float16)d[r];
            }
        }
        {
            const f32x4 d = __builtin_amdgcn_mfma_f32_16x16x32_f16(afA, bf, z4, 0, 0, 0);
            if (q == 0) {
                #pragma unroll
                for (int r = 0; r < 4; ++r)
                    sP[p * PSTR + (64 + r) * 16 + ml] = (_Float16)d[r];
            }
        }
    }
    __syncthreads();

    const int o0 = w * 32;
    f32x4 acc0 = z4, acc1 = z4;
    const _Float16* aP  = sP + ml * PSTR + q * 8;
    const _Float16* bP0 = LWh + (o0 + ml) * FP + q * 8;
    const _Float16* bP1 = bP0 + 16 * FP;
    #pragma unroll 2
    for (int ch = 0; ch < 34; ++ch) {
        f16x8 a  = *(const f16x8*)(aP  + ch * 32);
        f16x8 b0 = *(const f16x8*)(bP0 + ch * 32);
        f16x8 b1 = *(const f16x8*)(bP1 + ch * 32);
        acc0 = __builtin_amdgcn_mfma_f32_16x16x32_f16(a, b0, acc0, 0, 0, 0);
        acc1 = __builtin_amdgcn_mfma_f32_16x16x32_f16(a, b1, acc1, 0, 0, 0);
    }
    const float bz0 = bias[o0 + ml], bz1 = bias[o0 + 16 + ml];
    float* obase = out + (bN + n0 + q * 4) * 128;
    #pragma unroll
    for (int r = 0; r < 4; ++r) {
        obase[r * 128 + o0 + ml]      = acc0[r] + bz0;
        obase[r * 128 + o0 + 16 + ml] = acc1[r] + bz1;
    }
}

extern "C" void kernel_launch(void* const* d_in, const int* in_sizes, int n_in,
                              void* d_out, int out_size, void* d_ws, size_t ws_size,
                              hipStream_t stream)
{
    const float* inF  = (const float*)d_in[0];
    const int*   inds = (const int*)  d_in[1];
    const float* Wn   = (const float*)d_in[2];
    const float* addF = (const float*)d_in[3];
    const float* LW   = (const float*)d_in[4];
    const float* bias = (const float*)d_in[5];
    float* out = (float*)d_out;

    const size_t LWH_SZ = (size_t)128 * FP * 2;          // 278,528 B (256B-aligned)
    _Float16* LWh = (_Float16*)d_ws;
    _Float16* P   = (_Float16*)((char*)d_ws + LWH_SZ);

    int chunk = 0;
    if (ws_size >= LWH_SZ + (size_t)15000 * FP * 2) chunk = 15000;       // 32.9 MB
    else if (ws_size >= LWH_SZ + (size_t)3000 * FP * 2) chunk = 3000;    //  6.8 MB

    cvt_lw_kernel<<<dim3(128), dim3(256), 0, stream>>>(LW, LWh);

    if (chunk) {
        for (int c0 = 0; c0 < TOTP; c0 += chunk) {
            pconv_gather<<<dim3(chunk / 8), dim3(256), 0, stream>>>(
                inF, inds, Wn, addF, P, c0);
            linear_mfma<<<dim3((chunk + 127) / 128), dim3(256), 0, stream>>>(
                P, LWh, bias, out, c0, chunk);
        }
    } else {
        pconv_linear_fused<<<dim3(7500), dim3(256), 0, stream>>>(
            inF, inds, Wn, addF, LWh, bias, out);
    }
}